// Round 1
// baseline (5074.223 us; speedup 1.0000x reference)
//
#include <hip/hip_runtime.h>
#include <cstddef>

#define S3 32768  // 32*32*32 spatial positions

// ---------------- Kernel 1: token = mixer_w @ basis ; q = wq[4] @ token ----
__global__ __launch_bounds__(256) void token_q_kernel(
    const float* __restrict__ basis, const float* __restrict__ mixer,
    const float* __restrict__ wq, float* __restrict__ token,
    float* __restrict__ qbuf)
{
    int s = blockIdx.x * 256 + threadIdx.x;  // 0..32767
    float tok[32];
#pragma unroll
    for (int c = 0; c < 32; ++c) tok[c] = 0.f;
#pragma unroll
    for (int r = 0; r < 8; ++r) {
        float bv = basis[r * S3 + s];
#pragma unroll
        for (int c = 0; c < 32; ++c) tok[c] += mixer[c * 8 + r] * bv;
    }
#pragma unroll
    for (int c = 0; c < 32; ++c) token[c * S3 + s] = tok[c];

    const float* wq4 = wq + 4 * 32 * 32;
    for (int o = 0; o < 32; ++o) {
        float a = 0.f;
#pragma unroll
        for (int c = 0; c < 32; ++c) a += wq4[o * 32 + c] * tok[c];
        qbuf[o * S3 + s] = a;
    }
}

// ---------------- Kernel 2: row-4 attention, writes alpha*att into d_out ---
__global__ __launch_bounds__(256) void attention_kernel(
    const float* __restrict__ x, const float* __restrict__ token,
    const float* __restrict__ qbuf, const float* __restrict__ wk,
    const float* __restrict__ wv, const float* __restrict__ alpha_p,
    float* __restrict__ out)
{
    int t = blockIdx.x * 256 + threadIdx.x;  // 0..131071
    int s = t & (S3 - 1);
    int b = t >> 15;

    float q[32];
#pragma unroll
    for (int c = 0; c < 32; ++c) q[c] = qbuf[c * S3 + s];

    const float scale = 0.17677669529663687f;  // 1/sqrt(32)
    float l[5];
#pragma unroll
    for (int j = 0; j < 5; ++j) {
        float xv[32];
        const float* xp = (j < 4) ? (x + ((size_t)b * 128 + j * 32) * S3) : token;
#pragma unroll
        for (int c = 0; c < 32; ++c) xv[c] = xp[(size_t)c * S3 + s];
        const float* wkj = wk + j * 1024;
        float acc = 0.f;
        for (int o = 0; o < 32; ++o) {
            float kv = 0.f;
#pragma unroll
            for (int c = 0; c < 32; ++c) kv += wkj[o * 32 + c] * xv[c];
            acc += q[o] * kv;
        }
        l[j] = acc * scale;
    }
    float m = l[0];
#pragma unroll
    for (int j = 1; j < 5; ++j) m = fmaxf(m, l[j]);
    float p[5], sum = 0.f;
#pragma unroll
    for (int j = 0; j < 5; ++j) { p[j] = __expf(l[j] - m); sum += p[j]; }
    float inv = alpha_p[0] / sum;  // fold alpha into normalization

    float ov[32];
#pragma unroll
    for (int o = 0; o < 32; ++o) ov[o] = 0.f;
#pragma unroll
    for (int j = 0; j < 5; ++j) {
        float xv[32];
        const float* xp = (j < 4) ? (x + ((size_t)b * 128 + j * 32) * S3) : token;
#pragma unroll
        for (int c = 0; c < 32; ++c) xv[c] = xp[(size_t)c * S3 + s];
        const float* wvj = wv + j * 1024;
        float pj = p[j];
        for (int o = 0; o < 32; ++o) {
            float vv = 0.f;
#pragma unroll
            for (int c = 0; c < 32; ++c) vv += wvj[o * 32 + c] * xv[c];
            ov[o] += pj * vv;
        }
    }
#pragma unroll
    for (int o = 0; o < 32; ++o)
        out[((size_t)b * 32 + o) * S3 + s] = ov[o] * inv;
}

// ---------------- Conv 5x5x5 "same", direct, LDS-tiled ---------------------
// Block: 16 out-channels x (z:2, y:8, x:32) tile. 256 threads.
// Thread: 4 oc x 8 x-positions -> acc[4][8], inner loop 160 FMA / ~11 LDS ops.
template <int IC, int OC_TOTAL, bool GELU, bool ADD_ATT>
__global__ __launch_bounds__(256) void conv5_kernel(
    const float* __restrict__ in, const float* __restrict__ w,
    const float* __restrict__ bias, const float* __restrict__ att,
    float* __restrict__ out)
{
    __shared__ float in_t[6 * 12 * 36];   // [z 6][y 12][x 36], x shifted by +2
    __shared__ float w_t[16 * 25 * 8];    // [oc 16][dzdy 25][dx 8-padded]

    const int tid = threadIdx.x;
    const int zb = blockIdx.x >> 2, yb = blockIdx.x & 3;
    const int z0 = zb * 2, y0 = yb * 8;
    const int ocb = blockIdx.y, b = blockIdx.z;
    const int oc_base = ocb * 16;

    const int xq = tid & 3, ty = (tid >> 2) & 7, tz = (tid >> 5) & 1, ocq = tid >> 6;
    const int x0 = xq * 8;
    const int z = z0 + tz, y = y0 + ty;

    float acc[4][8];
#pragma unroll
    for (int o = 0; o < 4; ++o)
#pragma unroll
        for (int p = 0; p < 8; ++p) acc[o][p] = 0.f;

    const float* inb = in + (size_t)b * IC * S3;
    const int wstride = IC * 125;

    for (int ic = 0; ic < IC; ++ic) {
        // stage input tile (zero-padded halo): 6*12*36 = 2592 floats
        for (int i = tid; i < 2592; i += 256) {
            int lz = i / 432;
            int rem = i - lz * 432;
            int ly = rem / 36;
            int lx = rem - ly * 36;
            int gz = z0 - 2 + lz, gy = y0 - 2 + ly, gx = lx - 2;
            float v = 0.f;
            if ((unsigned)gz < 32u && (unsigned)gy < 32u && (unsigned)gx < 32u)
                v = inb[(size_t)ic * S3 + gz * 1024 + gy * 32 + gx];
            in_t[i] = v;
        }
        // stage weights: 16 oc * 125 taps (dx padded to 8)
        for (int i = tid; i < 2000; i += 256) {
            int o = i / 125;
            int r = i - o * 125;
            int dzy = r / 5;
            int dx = r - dzy * 5;
            w_t[o * 200 + dzy * 8 + dx] =
                w[(size_t)(oc_base + o) * wstride + ic * 125 + r];
        }
        __syncthreads();

#pragma unroll
        for (int dz = 0; dz < 5; ++dz) {
#pragma unroll
            for (int dy = 0; dy < 5; ++dy) {
                const float4* rowp =
                    (const float4*)&in_t[((tz + dz) * 12 + (ty + dy)) * 36 + x0];
                float4 a0 = rowp[0], a1 = rowp[1], a2 = rowp[2];
                float win[12] = {a0.x, a0.y, a0.z, a0.w, a1.x, a1.y,
                                 a1.z, a1.w, a2.x, a2.y, a2.z, a2.w};
#pragma unroll
                for (int o = 0; o < 4; ++o) {
                    const float* wrow = &w_t[(ocq * 4 + o) * 200 + (dz * 5 + dy) * 8];
                    float4 w0 = *(const float4*)wrow;
                    float wv[5] = {w0.x, w0.y, w0.z, w0.w, wrow[4]};
#pragma unroll
                    for (int dx = 0; dx < 5; ++dx)
#pragma unroll
                        for (int p = 0; p < 8; ++p)
                            acc[o][p] += wv[dx] * win[p + dx];
                }
            }
        }
        __syncthreads();
    }

#pragma unroll
    for (int o = 0; o < 4; ++o) {
        int oc = oc_base + ocq * 4 + o;
        float bv = bias[oc];
        size_t base = ((size_t)b * OC_TOTAL + oc) * S3 + z * 1024 + y * 32 + x0;
#pragma unroll
        for (int p = 0; p < 8; ++p) {
            float v = acc[o][p] + bv;
            if (GELU) v = 0.5f * v * (1.f + erff(v * 0.7071067811865476f));
            if (ADD_ATT) v += att[base + p];
            out[base + p] = v;
        }
    }
}

// ---------------------------------------------------------------------------
extern "C" void kernel_launch(void* const* d_in, const int* in_sizes, int n_in,
                              void* d_out, int out_size, void* d_ws, size_t ws_size,
                              hipStream_t stream)
{
    const float* x       = (const float*)d_in[0];   // (4,4,32,32,32,32)
    const float* basis   = (const float*)d_in[1];   // (1,8,32,32,32)
    const float* mixer   = (const float*)d_in[2];   // (32,8)
    const float* wq      = (const float*)d_in[3];   // (5,32,32)
    const float* wk      = (const float*)d_in[4];
    const float* wv      = (const float*)d_in[5];
    const float* conv1_w = (const float*)d_in[6];   // (64,128,5,5,5)
    const float* conv1_b = (const float*)d_in[7];
    const float* conv2_w = (const float*)d_in[8];   // (32,64,5,5,5)
    const float* conv2_b = (const float*)d_in[9];
    const float* alpha   = (const float*)d_in[10];
    float* out = (float*)d_out;                     // (4,32,32,32,32)

    float* ws    = (float*)d_ws;
    float* token = ws;                // 32*32768   = 1,048,576 floats (4 MiB)
    float* qbuf  = ws + 1048576;      // 1,048,576 floats (4 MiB)
    float* h     = ws + 2097152;      // 4*64*32768 = 8,388,608 floats (32 MiB)

    // 1) token + q
    token_q_kernel<<<S3 / 256, 256, 0, stream>>>(basis, mixer, wq, token, qbuf);

    // 2) attention row-4 -> d_out = alpha * att
    attention_kernel<<<(4 * S3) / 256, 256, 0, stream>>>(x, token, qbuf, wk, wv,
                                                         alpha, out);

    // 3) conv1 + bias + gelu -> h
    {
        dim3 grid(64, 4, 4);  // (z-blocks*y-blocks, oc-blocks of 16, batch)
        conv5_kernel<128, 64, true, false><<<grid, 256, 0, stream>>>(
            x, conv1_w, conv1_b, nullptr, h);
    }
    // 4) conv2 + bias + att(add from d_out) -> d_out
    {
        dim3 grid(64, 2, 4);
        conv5_kernel<64, 32, false, true><<<grid, 256, 0, stream>>>(
            h, conv2_w, conv2_b, out, out);
    }
}

// Round 2
// 1334.694 us; speedup vs baseline: 3.8018x; 3.8018x over previous
//
#include <hip/hip_runtime.h>
#include <cstddef>
#include <cstdint>

#define S3 32768  // 32*32*32 spatial positions

typedef short bf16x8 __attribute__((ext_vector_type(8)));   // 8 bf16 in 4 VGPRs
typedef float f32x16 __attribute__((ext_vector_type(16)));

static __device__ inline unsigned short f2bf(float f) {
    unsigned int u = __float_as_uint(f);
    unsigned int r = (u + 0x7FFFu + ((u >> 16) & 1u)) >> 16;  // RNE
    return (unsigned short)r;
}

// ---------------- weight transpose: wT[tap][icb][oc][32ic] bf16 ------------
template <int IC, int OC>
__global__ __launch_bounds__(256) void wt_transpose(
    const float* __restrict__ w, unsigned short* __restrict__ wT)
{
    int t = blockIdx.x * 256 + threadIdx.x;  // < 125*IC*OC
    int ic = t & 31;
    int rest = t >> 5;
    int oc = rest % OC; rest /= OC;
    int icb = rest % (IC / 32);
    int tap = rest / (IC / 32);
    wT[t] = f2bf(w[((size_t)oc * IC + icb * 32 + ic) * 125 + tap]);
}

// ---------------- x transpose: xb[b][z][y][x][128 ic] bf16 -----------------
__global__ __launch_bounds__(256) void xb_transpose(
    const float* __restrict__ x, unsigned short* __restrict__ xb)
{
    __shared__ float tile[32][133];
    int zy = blockIdx.x, b = blockIdx.y;
    int t = threadIdx.x, xi = t & 31, ich = t >> 5;
#pragma unroll
    for (int k = 0; k < 16; ++k) {
        int ic = k * 8 + ich;
        tile[xi][ic] = x[(size_t)(b * 128 + ic) * S3 + zy * 32 + xi];
    }
    __syncthreads();
#pragma unroll
    for (int k = 0; k < 2; ++k) {
        int u = t + 256 * k;
        int xx = u >> 4, j = u & 15;
        __align__(16) unsigned short tmp[8];
#pragma unroll
        for (int e = 0; e < 8; ++e) tmp[e] = f2bf(tile[xx][j * 8 + e]);
        *(uint4*)(xb + ((size_t)b * S3 + zy * 32 + xx) * 128 + j * 8) =
            *(const uint4*)tmp;
    }
}

// ---------------- attention (row 4 only), writes alpha*att into d_out ------
__global__ __launch_bounds__(256) void attention_kernel(
    const float* __restrict__ x, const float* __restrict__ basis,
    const float* __restrict__ mixer, const float* __restrict__ wq,
    const float* __restrict__ wk, const float* __restrict__ wv,
    const float* __restrict__ alpha_p, float* __restrict__ out)
{
    int t = blockIdx.x * 256 + threadIdx.x;
    int s = t & (S3 - 1);
    int b = t >> 15;

    float tok[32];
#pragma unroll
    for (int c = 0; c < 32; ++c) tok[c] = 0.f;
#pragma unroll
    for (int r = 0; r < 8; ++r) {
        float bv = basis[r * S3 + s];
#pragma unroll
        for (int c = 0; c < 32; ++c) tok[c] += mixer[c * 8 + r] * bv;
    }
    const float* wq4 = wq + 4 * 1024;
    float q[32];
    for (int o = 0; o < 32; ++o) {
        float a = 0.f;
#pragma unroll
        for (int c = 0; c < 32; ++c) a += wq4[o * 32 + c] * tok[c];
        q[o] = a;
    }

    const float scale = 0.17677669529663687f;
    float l[5];
#pragma unroll
    for (int j = 0; j < 5; ++j) {
        float xv[32];
        const float* xp = (j < 4) ? (x + ((size_t)b * 128 + j * 32) * S3) : nullptr;
#pragma unroll
        for (int c = 0; c < 32; ++c) xv[c] = (j < 4) ? xp[(size_t)c * S3 + s] : tok[c];
        const float* wkj = wk + j * 1024;
        float acc = 0.f;
        for (int o = 0; o < 32; ++o) {
            float kv = 0.f;
#pragma unroll
            for (int c = 0; c < 32; ++c) kv += wkj[o * 32 + c] * xv[c];
            acc += q[o] * kv;
        }
        l[j] = acc * scale;
    }
    float m = l[0];
#pragma unroll
    for (int j = 1; j < 5; ++j) m = fmaxf(m, l[j]);
    float p[5], sum = 0.f;
#pragma unroll
    for (int j = 0; j < 5; ++j) { p[j] = __expf(l[j] - m); sum += p[j]; }
    float inv = alpha_p[0] / sum;

    float ov[32];
#pragma unroll
    for (int o = 0; o < 32; ++o) ov[o] = 0.f;
#pragma unroll
    for (int j = 0; j < 5; ++j) {
        float xv[32];
        const float* xp = (j < 4) ? (x + ((size_t)b * 128 + j * 32) * S3) : nullptr;
#pragma unroll
        for (int c = 0; c < 32; ++c) xv[c] = (j < 4) ? xp[(size_t)c * S3 + s] : tok[c];
        const float* wvj = wv + j * 1024;
        float pj = p[j];
        for (int o = 0; o < 32; ++o) {
            float vv = 0.f;
#pragma unroll
            for (int c = 0; c < 32; ++c) vv += wvj[o * 32 + c] * xv[c];
            ov[o] += pj * vv;
        }
    }
#pragma unroll
    for (int o = 0; o < 32; ++o)
        out[((size_t)b * 32 + o) * S3 + s] = ov[o] * inv;
}

// ---------------- implicit-GEMM 5x5x5 conv via MFMA 32x32x16 bf16 ----------
// Block: 64(or 32) oc x (16 y x 32 x) at one z. 4 waves; wave-tile OC x 128 pos
// (4 y-rows). K-loop: icb(32) x dz x dy x dx x kb(16).
// xin: [b][z][y][x][IC] bf16. wT: [tap][IC/32][OC][32] bf16.
template <int IC, int OC, bool WRITE_H>
__global__ __launch_bounds__(256, 1) void conv_mfma(
    const unsigned short* __restrict__ xin, const unsigned short* __restrict__ wT,
    const float* __restrict__ bias, unsigned short* __restrict__ hout,
    float* __restrict__ fout)
{
    constexpr int NOC = OC / 32;
    __shared__ __align__(16) char lds_in[20 * 36 * 80];  // [row20][x36][32ic pad80B]
    __shared__ __align__(16) char lds_w[5 * OC * 80];    // [dx5][oc][32ic pad80B]

    const int tid = threadIdx.x;
    const int wave = tid >> 6, lane = tid & 63;
    const int ln = lane & 31, half = lane >> 5;
    const int z = blockIdx.x, ybl = blockIdx.y, b = blockIdx.z;
    const int y0 = ybl * 16;

    f32x16 acc[NOC][4];
#pragma unroll
    for (int c = 0; c < NOC; ++c)
#pragma unroll
        for (int j = 0; j < 4; ++j)
#pragma unroll
            for (int e = 0; e < 16; ++e) acc[c][j][e] = 0.f;

    for (int icb = 0; icb < IC / 32; ++icb) {
        for (int dz = 0; dz < 5; ++dz) {
            __syncthreads();  // protect lds_in readers from previous iter
            int gz = z + dz - 2;
            // stage input: 20 rows (y0-2..y0+17) x 36 x (x -2..33) x 32 ic
            for (int i = tid; i < 2880; i += 256) {
                int sub = i & 3, cc = i >> 2;
                int x36 = cc % 36, row = cc / 36;
                int gy = y0 - 2 + row, gx = x36 - 2;
                uint4 v = {0u, 0u, 0u, 0u};
                if ((unsigned)gz < 32u && (unsigned)gy < 32u && (unsigned)gx < 32u)
                    v = *(const uint4*)(xin +
                        ((((size_t)b * 32 + gz) * 32 + gy) * 32 + gx) * IC +
                        icb * 32 + sub * 8);
                *(uint4*)(lds_in + row * 2880 + x36 * 80 + sub * 16) = v;
            }
            for (int dy = 0; dy < 5; ++dy) {
                __syncthreads();  // protect lds_w readers (also covers input stage)
                for (int i = tid; i < 5 * OC * 4; i += 256) {
                    int sub = i & 3, cc = i >> 2;
                    int oc = cc % OC, dx = cc / OC;
                    int tap = (dz * 5 + dy) * 5 + dx;
                    uint4 v = *(const uint4*)(wT +
                        (((size_t)tap * (IC / 32) + icb) * OC + oc) * 32 + sub * 8);
                    *(uint4*)(lds_w + (dx * OC + oc) * 80 + sub * 16) = v;
                }
                __syncthreads();
#pragma unroll
                for (int dx = 0; dx < 5; ++dx) {
#pragma unroll
                    for (int kb = 0; kb < 2; ++kb) {
                        bf16x8 af[NOC];
#pragma unroll
                        for (int c = 0; c < NOC; ++c)
                            af[c] = *(const bf16x8*)(lds_w +
                                (dx * OC + c * 32 + ln) * 80 + kb * 32 + half * 16);
#pragma unroll
                        for (int j = 0; j < 4; ++j) {
                            bf16x8 bfr = *(const bf16x8*)(lds_in +
                                (4 * wave + j + dy) * 2880 + (ln + dx) * 80 +
                                kb * 32 + half * 16);
#pragma unroll
                            for (int c = 0; c < NOC; ++c)
                                acc[c][j] = __builtin_amdgcn_mfma_f32_32x32x16_bf16(
                                    af[c], bfr, acc[c][j], 0, 0, 0);
                        }
                    }
                }
            }
        }
    }

    __syncthreads();
    if (WRITE_H) {
        // bias + exact GELU, transpose to [x][oc] via per-wave LDS scratch,
        // store h[b][z][y][x][OC] bf16 (conv2's staging layout).
        char* scr = lds_in + wave * (32 * 144);
        for (int j = 0; j < 4; ++j) {
            int y = y0 + 4 * wave + j;
#pragma unroll
            for (int c = 0; c < NOC; ++c)
#pragma unroll
                for (int r = 0; r < 16; ++r) {
                    int oc = c * 32 + (r & 3) + 8 * (r >> 2) + 4 * half;
                    float v = acc[c][j][r] + bias[oc];
                    v = 0.5f * v * (1.f + erff(v * 0.70710678118654752f));
                    *(unsigned short*)(scr + ln * 144 + oc * 2) = f2bf(v);
                }
            __syncthreads();
#pragma unroll
            for (int k = 0; k < OC / 16; ++k) {
                int u = lane + 64 * k;          // 16B units, OC/8 per x
                int xx = u / (OC / 8), un = u % (OC / 8);
                uint4 v = *(const uint4*)(scr + xx * 144 + un * 16);
                *(uint4*)(hout + ((((size_t)b * 32 + z) * 32 + y) * 32 + xx) * OC +
                          un * 8) = v;
            }
            __syncthreads();
        }
    } else {
        // final: bias + attention (already alpha-scaled in fout) added in place
        for (int j = 0; j < 4; ++j) {
            int y = y0 + 4 * wave + j;
#pragma unroll
            for (int r = 0; r < 16; ++r) {
                int oc = (r & 3) + 8 * (r >> 2) + 4 * half;
                size_t o = ((size_t)b * OC + oc) * S3 + z * 1024 + y * 32 + ln;
                fout[o] = acc[0][j][r] + bias[oc] + fout[o];
            }
        }
    }
}

// ---------------------------------------------------------------------------
extern "C" void kernel_launch(void* const* d_in, const int* in_sizes, int n_in,
                              void* d_out, int out_size, void* d_ws, size_t ws_size,
                              hipStream_t stream)
{
    const float* x       = (const float*)d_in[0];
    const float* basis   = (const float*)d_in[1];
    const float* mixer   = (const float*)d_in[2];
    const float* wq      = (const float*)d_in[3];
    const float* wk      = (const float*)d_in[4];
    const float* wv      = (const float*)d_in[5];
    const float* conv1_w = (const float*)d_in[6];
    const float* conv1_b = (const float*)d_in[7];
    const float* conv2_w = (const float*)d_in[8];
    const float* conv2_b = (const float*)d_in[9];
    const float* alpha   = (const float*)d_in[10];
    float* out = (float*)d_out;

    char* wsb = (char*)d_ws;
    unsigned short* xb  = (unsigned short*)wsb;               // 32 MiB
    unsigned short* h   = (unsigned short*)(wsb + 33554432);  // 16 MiB
    unsigned short* wT1 = (unsigned short*)(wsb + 50331648);  // 2 MiB
    unsigned short* wT2 = (unsigned short*)(wsb + 52379648);  // 0.5 MiB

    wt_transpose<128, 64><<<4000, 256, 0, stream>>>(conv1_w, wT1);
    wt_transpose<64, 32><<<1000, 256, 0, stream>>>(conv2_w, wT2);
    xb_transpose<<<dim3(1024, 4), 256, 0, stream>>>(x, xb);

    attention_kernel<<<512, 256, 0, stream>>>(x, basis, mixer, wq, wk, wv,
                                              alpha, out);

    conv_mfma<128, 64, true><<<dim3(32, 2, 4), 256, 0, stream>>>(
        xb, wT1, conv1_b, h, nullptr);
    conv_mfma<64, 32, false><<<dim3(32, 2, 4), 256, 0, stream>>>(
        h, wT2, conv2_b, nullptr, out);
}

// Round 3
// 847.084 us; speedup vs baseline: 5.9902x; 1.5756x over previous
//
#include <hip/hip_runtime.h>
#include <cstddef>
#include <cstdint>

#define S3 32768  // 32*32*32 spatial positions

typedef short bf16x8 __attribute__((ext_vector_type(8)));   // 8 bf16 in 4 VGPRs
typedef float f32x16 __attribute__((ext_vector_type(16)));

static __device__ inline unsigned short f2bf(float f) {
    unsigned int u = __float_as_uint(f);
    unsigned int r = (u + 0x7FFFu + ((u >> 16) & 1u)) >> 16;  // RNE
    return (unsigned short)r;
}

// ---------------- weight transpose: wT[tap][icb][oc][32ic] bf16 ------------
template <int IC, int OC>
__global__ __launch_bounds__(256) void wt_transpose(
    const float* __restrict__ w, unsigned short* __restrict__ wT)
{
    int t = blockIdx.x * 256 + threadIdx.x;  // < 125*IC*OC
    int ic = t & 31;
    int rest = t >> 5;
    int oc = rest % OC; rest /= OC;
    int icb = rest % (IC / 32);
    int tap = rest / (IC / 32);
    wT[t] = f2bf(w[((size_t)oc * IC + icb * 32 + ic) * 125 + tap]);
}

// ---------------- x transpose: xb[b][z][y][x][128 ic] bf16 -----------------
__global__ __launch_bounds__(256) void xb_transpose(
    const float* __restrict__ x, unsigned short* __restrict__ xb)
{
    __shared__ float tile[32][133];
    int zy = blockIdx.x, b = blockIdx.y;
    int t = threadIdx.x, xi = t & 31, ich = t >> 5;
#pragma unroll
    for (int k = 0; k < 16; ++k) {
        int ic = k * 8 + ich;
        tile[xi][ic] = x[(size_t)(b * 128 + ic) * S3 + zy * 32 + xi];
    }
    __syncthreads();
#pragma unroll
    for (int k = 0; k < 2; ++k) {
        int u = t + 256 * k;
        int xx = u >> 4, j = u & 15;
        __align__(16) unsigned short tmp[8];
#pragma unroll
        for (int e = 0; e < 8; ++e) tmp[e] = f2bf(tile[xx][j * 8 + e]);
        *(uint4*)(xb + ((size_t)b * S3 + zy * 32 + xx) * 128 + j * 8) =
            *(const uint4*)tmp;
    }
}

// ---------------- attention (row 4 only), writes alpha*att into d_out ------
__global__ __launch_bounds__(256) void attention_kernel(
    const float* __restrict__ x, const float* __restrict__ basis,
    const float* __restrict__ mixer, const float* __restrict__ wq,
    const float* __restrict__ wk, const float* __restrict__ wv,
    const float* __restrict__ alpha_p, float* __restrict__ out)
{
    int t = blockIdx.x * 256 + threadIdx.x;
    int s = t & (S3 - 1);
    int b = t >> 15;

    float tok[32];
#pragma unroll
    for (int c = 0; c < 32; ++c) tok[c] = 0.f;
#pragma unroll
    for (int r = 0; r < 8; ++r) {
        float bv = basis[r * S3 + s];
#pragma unroll
        for (int c = 0; c < 32; ++c) tok[c] += mixer[c * 8 + r] * bv;
    }
    const float* wq4 = wq + 4 * 1024;
    float q[32];
#pragma unroll
    for (int o = 0; o < 32; ++o) {
        float a = 0.f;
#pragma unroll
        for (int c = 0; c < 32; ++c) a += wq4[o * 32 + c] * tok[c];
        q[o] = a;
    }

    const float scale = 0.17677669529663687f;
    float l[5];
#pragma unroll
    for (int j = 0; j < 5; ++j) {
        float xv[32];
        const float* xp = (j < 4) ? (x + ((size_t)b * 128 + j * 32) * S3) : nullptr;
#pragma unroll
        for (int c = 0; c < 32; ++c) xv[c] = (j < 4) ? xp[(size_t)c * S3 + s] : tok[c];
        const float* wkj = wk + j * 1024;
        float acc = 0.f;
#pragma unroll
        for (int o = 0; o < 32; ++o) {
            float kv = 0.f;
#pragma unroll
            for (int c = 0; c < 32; ++c) kv += wkj[o * 32 + c] * xv[c];
            acc += q[o] * kv;
        }
        l[j] = acc * scale;
    }
    float m = l[0];
#pragma unroll
    for (int j = 1; j < 5; ++j) m = fmaxf(m, l[j]);
    float p[5], sum = 0.f;
#pragma unroll
    for (int j = 0; j < 5; ++j) { p[j] = __expf(l[j] - m); sum += p[j]; }
    float inv = alpha_p[0] / sum;

    float ov[32];
#pragma unroll
    for (int o = 0; o < 32; ++o) ov[o] = 0.f;
#pragma unroll
    for (int j = 0; j < 5; ++j) {
        float xv[32];
        const float* xp = (j < 4) ? (x + ((size_t)b * 128 + j * 32) * S3) : nullptr;
#pragma unroll
        for (int c = 0; c < 32; ++c) xv[c] = (j < 4) ? xp[(size_t)c * S3 + s] : tok[c];
        const float* wvj = wv + j * 1024;
        float pj = p[j];
#pragma unroll
        for (int o = 0; o < 32; ++o) {
            float vv = 0.f;
#pragma unroll
            for (int c = 0; c < 32; ++c) vv += wvj[o * 32 + c] * xv[c];
            ov[o] += pj * vv;
        }
    }
#pragma unroll
    for (int o = 0; o < 32; ++o)
        out[((size_t)b * 32 + o) * S3 + s] = ov[o] * inv;
}

// ---------------- implicit-GEMM 5x5x5 conv via MFMA 32x32x16 bf16 ----------
// Block: 64(or 32) oc x (16 y x 32 x) at one z. 4 waves; wave-tile OC x 128 pos
// (4 y-rows). K-loop: icb(32) x dz x dy x dx x kb(16).
// xin: [b][z][y][x][IC] bf16. wT: [tap][IC/32][OC][32] bf16.
template <int IC, int OC, bool WRITE_H>
__global__ __launch_bounds__(256, 1) void conv_mfma(
    const unsigned short* __restrict__ xin, const unsigned short* __restrict__ wT,
    const float* __restrict__ bias, unsigned short* __restrict__ hout,
    float* __restrict__ fout)
{
    constexpr int NOC = OC / 32;
    __shared__ __align__(16) char lds_in[20 * 36 * 80];  // [row20][x36][32ic pad80B]
    __shared__ __align__(16) char lds_w[5 * OC * 80];    // [dx5][oc][32ic pad80B]

    const int tid = threadIdx.x;
    const int wave = tid >> 6, lane = tid & 63;
    const int ln = lane & 31, half = lane >> 5;
    const int z = blockIdx.x, ybl = blockIdx.y, b = blockIdx.z;
    const int y0 = ybl * 16;

    f32x16 acc[NOC][4];
#pragma unroll
    for (int c = 0; c < NOC; ++c)
#pragma unroll
        for (int j = 0; j < 4; ++j)
#pragma unroll
            for (int e = 0; e < 16; ++e) acc[c][j][e] = 0.f;

    for (int icb = 0; icb < IC / 32; ++icb) {
        for (int dz = 0; dz < 5; ++dz) {
            __syncthreads();  // protect lds_in readers from previous iter
            int gz = z + dz - 2;
            // stage input: 20 rows (y0-2..y0+17) x 36 x (x -2..33) x 32 ic
            for (int i = tid; i < 2880; i += 256) {
                int sub = i & 3, cc = i >> 2;
                int x36 = cc % 36, row = cc / 36;
                int gy = y0 - 2 + row, gx = x36 - 2;
                uint4 v = {0u, 0u, 0u, 0u};
                if ((unsigned)gz < 32u && (unsigned)gy < 32u && (unsigned)gx < 32u)
                    v = *(const uint4*)(xin +
                        ((((size_t)b * 32 + gz) * 32 + gy) * 32 + gx) * IC +
                        icb * 32 + sub * 8);
                *(uint4*)(lds_in + row * 2880 + x36 * 80 + sub * 16) = v;
            }
            for (int dy = 0; dy < 5; ++dy) {
                __syncthreads();  // protect lds_w readers (also covers input stage)
                for (int i = tid; i < 5 * OC * 4; i += 256) {
                    int sub = i & 3, cc = i >> 2;
                    int oc = cc % OC, dx = cc / OC;
                    int tap = (dz * 5 + dy) * 5 + dx;
                    uint4 v = *(const uint4*)(wT +
                        (((size_t)tap * (IC / 32) + icb) * OC + oc) * 32 + sub * 8);
                    *(uint4*)(lds_w + (dx * OC + oc) * 80 + sub * 16) = v;
                }
                __syncthreads();
#pragma unroll
                for (int dx = 0; dx < 5; ++dx) {
#pragma unroll
                    for (int kb = 0; kb < 2; ++kb) {
                        bf16x8 af[NOC];
#pragma unroll
                        for (int c = 0; c < NOC; ++c)
                            af[c] = *(const bf16x8*)(lds_w +
                                (dx * OC + c * 32 + ln) * 80 + kb * 32 + half * 16);
#pragma unroll
                        for (int j = 0; j < 4; ++j) {
                            bf16x8 bfr = *(const bf16x8*)(lds_in +
                                (4 * wave + j + dy) * 2880 + (ln + dx) * 80 +
                                kb * 32 + half * 16);
#pragma unroll
                            for (int c = 0; c < NOC; ++c)
                                acc[c][j] = __builtin_amdgcn_mfma_f32_32x32x16_bf16(
                                    af[c], bfr, acc[c][j], 0, 0, 0);
                        }
                    }
                }
            }
        }
    }

    __syncthreads();
    if (WRITE_H) {
        // bias + exact GELU, transpose to [x][oc] via per-wave LDS scratch,
        // store h[b][z][y][x][OC] bf16 (conv2's staging layout).
        char* scr = lds_in + wave * (32 * 144);
#pragma unroll
        for (int j = 0; j < 4; ++j) {
            int y = y0 + 4 * wave + j;
#pragma unroll
            for (int c = 0; c < NOC; ++c)
#pragma unroll
                for (int r = 0; r < 16; ++r) {
                    int oc = c * 32 + (r & 3) + 8 * (r >> 2) + 4 * half;
                    float v = acc[c][j][r] + bias[oc];
                    v = 0.5f * v * (1.f + erff(v * 0.70710678118654752f));
                    *(unsigned short*)(scr + ln * 144 + oc * 2) = f2bf(v);
                }
            __syncthreads();
#pragma unroll
            for (int k = 0; k < OC / 16; ++k) {
                int u = lane + 64 * k;          // 16B units, OC/8 per x
                int xx = u / (OC / 8), un = u % (OC / 8);
                uint4 v = *(const uint4*)(scr + xx * 144 + un * 16);
                *(uint4*)(hout + ((((size_t)b * 32 + z) * 32 + y) * 32 + xx) * OC +
                          un * 8) = v;
            }
            __syncthreads();
        }
    } else {
        // final: bias + attention (already alpha-scaled in fout) added in place
#pragma unroll
        for (int j = 0; j < 4; ++j) {
            int y = y0 + 4 * wave + j;
#pragma unroll
            for (int r = 0; r < 16; ++r) {
                int oc = (r & 3) + 8 * (r >> 2) + 4 * half;
                size_t o = ((size_t)b * OC + oc) * S3 + z * 1024 + y * 32 + ln;
                fout[o] = acc[0][j][r] + bias[oc] + fout[o];
            }
        }
    }
}

// ---------------------------------------------------------------------------
extern "C" void kernel_launch(void* const* d_in, const int* in_sizes, int n_in,
                              void* d_out, int out_size, void* d_ws, size_t ws_size,
                              hipStream_t stream)
{
    const float* x       = (const float*)d_in[0];
    const float* basis   = (const float*)d_in[1];
    const float* mixer   = (const float*)d_in[2];
    const float* wq      = (const float*)d_in[3];
    const float* wk      = (const float*)d_in[4];
    const float* wv      = (const float*)d_in[5];
    const float* conv1_w = (const float*)d_in[6];
    const float* conv1_b = (const float*)d_in[7];
    const float* conv2_w = (const float*)d_in[8];
    const float* conv2_b = (const float*)d_in[9];
    const float* alpha   = (const float*)d_in[10];
    float* out = (float*)d_out;

    char* wsb = (char*)d_ws;
    unsigned short* xb  = (unsigned short*)wsb;               // 32 MiB
    unsigned short* h   = (unsigned short*)(wsb + 33554432);  // 16 MiB
    unsigned short* wT1 = (unsigned short*)(wsb + 50331648);  // 2 MiB
    unsigned short* wT2 = (unsigned short*)(wsb + 52379648);  // 0.5 MiB

    wt_transpose<128, 64><<<4000, 256, 0, stream>>>(conv1_w, wT1);
    wt_transpose<64, 32><<<1000, 256, 0, stream>>>(conv2_w, wT2);
    xb_transpose<<<dim3(1024, 4), 256, 0, stream>>>(x, xb);

    attention_kernel<<<512, 256, 0, stream>>>(x, basis, mixer, wq, wk, wv,
                                              alpha, out);

    conv_mfma<128, 64, true><<<dim3(32, 2, 4), 256, 0, stream>>>(
        xb, wT1, conv1_b, h, nullptr);
    conv_mfma<64, 32, false><<<dim3(32, 2, 4), 256, 0, stream>>>(
        h, wT2, conv2_b, nullptr, out);
}

// Round 4
// 717.976 us; speedup vs baseline: 7.0674x; 1.1798x over previous
//
#include <hip/hip_runtime.h>
#include <cstddef>
#include <cstdint>

#define S3 32768  // 32*32*32 spatial positions

typedef short bf16x8 __attribute__((ext_vector_type(8)));   // 8 bf16 in 4 VGPRs
typedef float f32x16 __attribute__((ext_vector_type(16)));

static __device__ inline unsigned short f2bf(float f) {
    unsigned int u = __float_as_uint(f);
    unsigned int r = (u + 0x7FFFu + ((u >> 16) & 1u)) >> 16;  // RNE
    return (unsigned short)r;
}

// ---------------- weight transpose: wT[tap][icb][oc][32ic] bf16 ------------
template <int IC, int OC>
__global__ __launch_bounds__(256) void wt_transpose(
    const float* __restrict__ w, unsigned short* __restrict__ wT)
{
    int t = blockIdx.x * 256 + threadIdx.x;  // < 125*IC*OC
    int ic = t & 31;
    int rest = t >> 5;
    int oc = rest % OC; rest /= OC;
    int icb = rest % (IC / 32);
    int tap = rest / (IC / 32);
    wT[t] = f2bf(w[((size_t)oc * IC + icb * 32 + ic) * 125 + tap]);
}

// ---------------- x transpose: xb[b][z][y][x][128 ic] bf16 -----------------
__global__ __launch_bounds__(256) void xb_transpose(
    const float* __restrict__ x, unsigned short* __restrict__ xb)
{
    __shared__ float tile[32][133];
    int zy = blockIdx.x, b = blockIdx.y;
    int t = threadIdx.x, xi = t & 31, ich = t >> 5;
#pragma unroll
    for (int k = 0; k < 16; ++k) {
        int ic = k * 8 + ich;
        tile[xi][ic] = x[(size_t)(b * 128 + ic) * S3 + zy * 32 + xi];
    }
    __syncthreads();
#pragma unroll
    for (int k = 0; k < 2; ++k) {
        int u = t + 256 * k;
        int xx = u >> 4, j = u & 15;
        __align__(16) unsigned short tmp[8];
#pragma unroll
        for (int e = 0; e < 8; ++e) tmp[e] = f2bf(tile[xx][j * 8 + e]);
        *(uint4*)(xb + ((size_t)b * S3 + zy * 32 + xx) * 128 + j * 8) =
            *(const uint4*)tmp;
    }
}

// ---------------- attention (row 4 only), writes alpha*att into d_out ------
__global__ __launch_bounds__(256) void attention_kernel(
    const float* __restrict__ x, const float* __restrict__ basis,
    const float* __restrict__ mixer, const float* __restrict__ wq,
    const float* __restrict__ wk, const float* __restrict__ wv,
    const float* __restrict__ alpha_p, float* __restrict__ out)
{
    int t = blockIdx.x * 256 + threadIdx.x;
    int s = t & (S3 - 1);
    int b = t >> 15;

    float tok[32];
#pragma unroll
    for (int c = 0; c < 32; ++c) tok[c] = 0.f;
#pragma unroll
    for (int r = 0; r < 8; ++r) {
        float bv = basis[r * S3 + s];
#pragma unroll
        for (int c = 0; c < 32; ++c) tok[c] += mixer[c * 8 + r] * bv;
    }
    const float* wq4 = wq + 4 * 1024;
    float q[32];
#pragma unroll
    for (int o = 0; o < 32; ++o) {
        float a = 0.f;
#pragma unroll
        for (int c = 0; c < 32; ++c) a += wq4[o * 32 + c] * tok[c];
        q[o] = a;
    }

    const float scale = 0.17677669529663687f;
    float l[5];
#pragma unroll
    for (int j = 0; j < 5; ++j) {
        float xv[32];
        const float* xp = (j < 4) ? (x + ((size_t)b * 128 + j * 32) * S3) : nullptr;
#pragma unroll
        for (int c = 0; c < 32; ++c) xv[c] = (j < 4) ? xp[(size_t)c * S3 + s] : tok[c];
        const float* wkj = wk + j * 1024;
        float acc = 0.f;
#pragma unroll
        for (int o = 0; o < 32; ++o) {
            float kv = 0.f;
#pragma unroll
            for (int c = 0; c < 32; ++c) kv += wkj[o * 32 + c] * xv[c];
            acc += q[o] * kv;
        }
        l[j] = acc * scale;
    }
    float m = l[0];
#pragma unroll
    for (int j = 1; j < 5; ++j) m = fmaxf(m, l[j]);
    float p[5], sum = 0.f;
#pragma unroll
    for (int j = 0; j < 5; ++j) { p[j] = __expf(l[j] - m); sum += p[j]; }
    float inv = alpha_p[0] / sum;

    float ov[32];
#pragma unroll
    for (int o = 0; o < 32; ++o) ov[o] = 0.f;
#pragma unroll
    for (int j = 0; j < 5; ++j) {
        float xv[32];
        const float* xp = (j < 4) ? (x + ((size_t)b * 128 + j * 32) * S3) : nullptr;
#pragma unroll
        for (int c = 0; c < 32; ++c) xv[c] = (j < 4) ? xp[(size_t)c * S3 + s] : tok[c];
        const float* wvj = wv + j * 1024;
        float pj = p[j];
#pragma unroll
        for (int o = 0; o < 32; ++o) {
            float vv = 0.f;
#pragma unroll
            for (int c = 0; c < 32; ++c) vv += wvj[o * 32 + c] * xv[c];
            ov[o] += pj * vv;
        }
    }
#pragma unroll
    for (int o = 0; o < 32; ++o)
        out[((size_t)b * 32 + o) * S3 + s] = ov[o] * inv;
}

// ---------------- implicit-GEMM 5x5x5 conv via MFMA 32x32x16 bf16 ----------
// Block: OC x (YT y x 32 x) at one z. 4 waves; wave-tile OC x (YT/4 rows).
// YT=8 -> LDS 60 KB -> 2 blocks/CU, grid 512 -> 2 waves/SIMD.
// xin: [b][z][y][x][IC] bf16. wT: [tap][IC/32][OC][32] bf16.
template <int IC, int OC, int YT, bool WRITE_H>
__global__ __launch_bounds__(256, 2) void conv_mfma(
    const unsigned short* __restrict__ xin, const unsigned short* __restrict__ wT,
    const float* __restrict__ bias, unsigned short* __restrict__ hout,
    float* __restrict__ fout)
{
    constexpr int NOC = OC / 32;
    constexpr int JT = YT / 4;          // y-rows per wave
    constexpr int NROW = YT + 4;        // staged rows incl. halo
    __shared__ __align__(16) char lds_in[NROW * 36 * 80];  // [row][x36][32ic pad80B]
    __shared__ __align__(16) char lds_w[5 * OC * 80];      // [dx5][oc][32ic pad80B]

    const int tid = threadIdx.x;
    const int wave = tid >> 6, lane = tid & 63;
    const int ln = lane & 31, half = lane >> 5;
    const int z = blockIdx.x, ybl = blockIdx.y, b = blockIdx.z;
    const int y0 = ybl * YT;

    f32x16 acc[NOC][JT];
#pragma unroll
    for (int c = 0; c < NOC; ++c)
#pragma unroll
        for (int j = 0; j < JT; ++j)
#pragma unroll
            for (int e = 0; e < 16; ++e) acc[c][j][e] = 0.f;

    for (int icb = 0; icb < IC / 32; ++icb) {
        for (int dz = 0; dz < 5; ++dz) {
            __syncthreads();  // protect lds_in readers from previous iter
            int gz = z + dz - 2;
            // stage input: NROW rows x 36 x (x -2..33) x 32 ic
            for (int i = tid; i < NROW * 36 * 4; i += 256) {
                int sub = i & 3, cc = i >> 2;
                int x36 = cc % 36, row = cc / 36;
                int gy = y0 - 2 + row, gx = x36 - 2;
                uint4 v = {0u, 0u, 0u, 0u};
                if ((unsigned)gz < 32u && (unsigned)gy < 32u && (unsigned)gx < 32u)
                    v = *(const uint4*)(xin +
                        ((((size_t)b * 32 + gz) * 32 + gy) * 32 + gx) * IC +
                        icb * 32 + sub * 8);
                *(uint4*)(lds_in + row * 2880 + x36 * 80 + sub * 16) = v;
            }
            for (int dy = 0; dy < 5; ++dy) {
                __syncthreads();  // protect lds_w readers (also covers input stage)
                for (int i = tid; i < 5 * OC * 4; i += 256) {
                    int sub = i & 3, cc = i >> 2;
                    int oc = cc % OC, dx = cc / OC;
                    int tap = (dz * 5 + dy) * 5 + dx;
                    uint4 v = *(const uint4*)(wT +
                        (((size_t)tap * (IC / 32) + icb) * OC + oc) * 32 + sub * 8);
                    *(uint4*)(lds_w + (dx * OC + oc) * 80 + sub * 16) = v;
                }
                __syncthreads();
#pragma unroll
                for (int dx = 0; dx < 5; ++dx) {
#pragma unroll
                    for (int kb = 0; kb < 2; ++kb) {
                        bf16x8 af[NOC];
#pragma unroll
                        for (int c = 0; c < NOC; ++c)
                            af[c] = *(const bf16x8*)(lds_w +
                                (dx * OC + c * 32 + ln) * 80 + kb * 32 + half * 16);
#pragma unroll
                        for (int j = 0; j < JT; ++j) {
                            bf16x8 bfr = *(const bf16x8*)(lds_in +
                                (JT * wave + j + dy) * 2880 + (ln + dx) * 80 +
                                kb * 32 + half * 16);
#pragma unroll
                            for (int c = 0; c < NOC; ++c)
                                acc[c][j] = __builtin_amdgcn_mfma_f32_32x32x16_bf16(
                                    af[c], bfr, acc[c][j], 0, 0, 0);
                        }
                    }
                }
            }
        }
    }

    __syncthreads();
    if (WRITE_H) {
        // bias + exact GELU, transpose to [x][oc] via per-wave LDS scratch,
        // store h[b][z][y][x][OC] bf16 (conv2's staging layout).
        char* scr = lds_in + wave * (32 * 144);
#pragma unroll
        for (int j = 0; j < JT; ++j) {
            int y = y0 + JT * wave + j;
#pragma unroll
            for (int c = 0; c < NOC; ++c)
#pragma unroll
                for (int r = 0; r < 16; ++r) {
                    int oc = c * 32 + (r & 3) + 8 * (r >> 2) + 4 * half;
                    float v = acc[c][j][r] + bias[oc];
                    v = 0.5f * v * (1.f + erff(v * 0.70710678118654752f));
                    *(unsigned short*)(scr + ln * 144 + oc * 2) = f2bf(v);
                }
            __syncthreads();
#pragma unroll
            for (int k = 0; k < OC / 16; ++k) {
                int u = lane + 64 * k;          // 16B units, OC/8 per x
                int xx = u / (OC / 8), un = u % (OC / 8);
                uint4 v = *(const uint4*)(scr + xx * 144 + un * 16);
                *(uint4*)(hout + ((((size_t)b * 32 + z) * 32 + y) * 32 + xx) * OC +
                          un * 8) = v;
            }
            __syncthreads();
        }
    } else {
        // final: bias + attention (already alpha-scaled in fout) added in place
#pragma unroll
        for (int j = 0; j < JT; ++j) {
            int y = y0 + JT * wave + j;
#pragma unroll
            for (int r = 0; r < 16; ++r) {
                int oc = (r & 3) + 8 * (r >> 2) + 4 * half;
                size_t o = ((size_t)b * OC + oc) * S3 + z * 1024 + y * 32 + ln;
                fout[o] = acc[0][j][r] + bias[oc] + fout[o];
            }
        }
    }
}

// ---------------------------------------------------------------------------
extern "C" void kernel_launch(void* const* d_in, const int* in_sizes, int n_in,
                              void* d_out, int out_size, void* d_ws, size_t ws_size,
                              hipStream_t stream)
{
    const float* x       = (const float*)d_in[0];
    const float* basis   = (const float*)d_in[1];
    const float* mixer   = (const float*)d_in[2];
    const float* wq      = (const float*)d_in[3];
    const float* wk      = (const float*)d_in[4];
    const float* wv      = (const float*)d_in[5];
    const float* conv1_w = (const float*)d_in[6];
    const float* conv1_b = (const float*)d_in[7];
    const float* conv2_w = (const float*)d_in[8];
    const float* conv2_b = (const float*)d_in[9];
    const float* alpha   = (const float*)d_in[10];
    float* out = (float*)d_out;

    char* wsb = (char*)d_ws;
    unsigned short* xb  = (unsigned short*)wsb;               // 32 MiB
    unsigned short* h   = (unsigned short*)(wsb + 33554432);  // 16 MiB
    unsigned short* wT1 = (unsigned short*)(wsb + 50331648);  // 2 MiB
    unsigned short* wT2 = (unsigned short*)(wsb + 52379648);  // 0.5 MiB

    wt_transpose<128, 64><<<4000, 256, 0, stream>>>(conv1_w, wT1);
    wt_transpose<64, 32><<<1000, 256, 0, stream>>>(conv2_w, wT2);
    xb_transpose<<<dim3(1024, 4), 256, 0, stream>>>(x, xb);

    attention_kernel<<<512, 256, 0, stream>>>(x, basis, mixer, wq, wk, wv,
                                              alpha, out);

    conv_mfma<128, 64, 8, true><<<dim3(32, 4, 4), 256, 0, stream>>>(
        xb, wT1, conv1_b, h, nullptr);
    conv_mfma<64, 32, 8, false><<<dim3(32, 4, 4), 256, 0, stream>>>(
        h, wT2, conv2_b, nullptr, out);
}